// Round 15
// baseline (92.333 us; speedup 1.0000x reference)
//
#include <hip/hip_runtime.h>
#include <hip/hip_bf16.h>

typedef __attribute__((ext_vector_type(8))) short bf16x8;
typedef __attribute__((ext_vector_type(16))) float f32x16;
typedef __attribute__((ext_vector_type(4))) float f32x4;
typedef __attribute__((ext_vector_type(2))) float f32x2;
typedef unsigned short u16;

#define BN 2
#define HN 12
#define NN 2049
#define CN 64
#define NT 2048
#define BH 24
#define QSCL 0.1803368801111204f /* 0.125 * log2(e) */

__device__ __forceinline__ u16 f2bf(float x) {
  unsigned u = __builtin_bit_cast(unsigned, x);
  unsigned r = (u + 0x7fffu + ((u >> 16) & 1u)) >> 16;
  return (u16)r;
}

__device__ __forceinline__ unsigned cvt_pk(float lo, float hi) {
  unsigned r;
  asm("v_cvt_pk_bf16_f32 %0, %1, %2" : "=v"(r) : "v"(lo), "v"(hi));
  return r;
}

union PU {
  unsigned u[4];
  bf16x8 v;
};
union B8 {
  f32x2 h[2];
  bf16x8 v;
};

// ---------------- Kernel A: rope q,k -> bf16; sigma-transposed v; fused row-0 partials ----------------
__global__ __launch_bounds__(256) void rope_pack(
    const float* __restrict__ q, const float* __restrict__ k, const float* __restrict__ v,
    const int* __restrict__ qpos, const int* __restrict__ kpos,
    u16* __restrict__ Qr, u16* __restrict__ Kr, u16* __restrict__ Vt,
    float* __restrict__ S0, float* __restrict__ Pl, float* __restrict__ Po) {
  const int bh = blockIdx.x;  // 0..23
  const int t = blockIdx.y;   // 0..63 (32-token tiles)
  const int b = bh / HN;
  const int tid = threadIdx.x;
  const int wv = tid >> 6, l = tid & 63;

  __shared__ float lutc[1024], luts[1024];  // idx = pos*16 + f
  __shared__ u16 ldsV[64][36];
  __shared__ float q0s[64], k0s[64];
  __shared__ float osum[4][64];
  __shared__ float psum[4];

  const int n0 = 1 + t * 32;
  const size_t base0 = (size_t)bh * NN * CN;

  const float LF = 6.6438561897747253f / 16.0f;  // log2(100)/16
  for (int i = tid; i < 1024; i += 256) {
    const int pos = i >> 4, f = i & 15;
    const float inv = exp2f(-(float)f * LF);
    float sv, cv;
    sincosf((float)pos * inv, &sv, &cv);
    lutc[i] = cv;
    luts[i] = sv;
  }
  if (tid < 64) {
    q0s[tid] = q[base0 + tid];
    k0s[tid] = k[base0 + tid];
  }
  __syncthreads();

  float oacc = 0.f, pacc = 0.f;
#pragma unroll 2
  for (int i = 0; i < 8; ++i) {
    const int tok = i * 4 + wv;
    const int c = l;
    const int n = n0 + tok;
    const size_t base = base0 + (size_t)n * CN;
    const int cp = c & 31, f = cp & 15, axis = c >> 5;
    const int qp_ = qpos[((size_t)b * NN + n) * 2 + axis];
    const int kp_ = kpos[((size_t)b * NN + n) * 2 + axis];
    const float qa = q[base + c];
    const float ka = k[base + c];
    const float qrot = (cp < 16) ? -q[base + c + 16] : q[base + c - 16];
    const float krot = (cp < 16) ? -k[base + c + 16] : k[base + c - 16];
    Qr[((size_t)bh * NT + (n - 1)) * CN + c] =
        f2bf((qa * lutc[qp_ * 16 + f] + qrot * luts[qp_ * 16 + f]) * QSCL);
    Kr[((size_t)bh * NT + (n - 1)) * CN + c] =
        f2bf(ka * lutc[kp_ * 16 + f] + krot * luts[kp_ * 16 + f]);
    const float vv = v[base + c];
    ldsV[c][tok] = f2bf(vv);

    float pk = ka * q0s[c];
    float pq = qa * k0s[c];
    pk += __shfl_xor(pk, 1, 64);  pq += __shfl_xor(pq, 1, 64);
    pk += __shfl_xor(pk, 2, 64);  pq += __shfl_xor(pq, 2, 64);
    pk += __shfl_xor(pk, 4, 64);  pq += __shfl_xor(pq, 4, 64);
    pk += __shfl_xor(pk, 8, 64);  pq += __shfl_xor(pq, 8, 64);
    pk += __shfl_xor(pk, 16, 64); pq += __shfl_xor(pq, 16, 64);
    pk += __shfl_xor(pk, 32, 64); pq += __shfl_xor(pq, 32, 64);
    const float p = __builtin_amdgcn_exp2f(pk * QSCL);
    pacc += p;
    oacc += p * vv;
    if (l == 0) S0[(size_t)bh * NT + (n - 1)] = pq * QSCL;
  }
  osum[wv][l] = oacc;
  if (l == 0) psum[wv] = pacc;
  __syncthreads();

  for (int e = tid; e < 2048; e += 256) {
    const int c = e >> 5, tok = e & 31;
    const int T = t * 32 + tok;
    const int t6 = T & 63, ch = t6 >> 3, j = t6 & 7;
    const int pos = 16 * (ch >> 1) + 4 * (ch & 1) + 8 * (j >> 2) + (j & 3);
    Vt[((size_t)bh * CN + c) * NT + (T >> 6) * 64 + pos] = ldsV[c][tok];
  }
  if (tid < 64)
    Po[(size_t)(bh * 64 + t) * 64 + tid] =
        osum[0][tid] + osum[1][tid] + osum[2][tid] + osum[3][tid];
  if (tid == 0) Pl[bh * 64 + t] = psum[0] + psum[1] + psum[2] + psum[3];
}

// ---------------- Kernel C: combine row-0 partials (+ token-0 term) ----------------
__global__ __launch_bounds__(64) void row0_reduce(
    const float* __restrict__ q, const float* __restrict__ k, const float* __restrict__ v,
    const float* __restrict__ Pl, const float* __restrict__ Po, float* __restrict__ out) {
  const int bh = blockIdx.x;
  const int b = bh / HN, h = bh % HN;
  const int c = threadIdx.x;
  const size_t base0 = (size_t)bh * NN * CN;
  float pr = q[base0 + c] * k[base0 + c];
  pr += __shfl_xor(pr, 1, 64);
  pr += __shfl_xor(pr, 2, 64);
  pr += __shfl_xor(pr, 4, 64);
  pr += __shfl_xor(pr, 8, 64);
  pr += __shfl_xor(pr, 16, 64);
  pr += __shfl_xor(pr, 32, 64);
  const float p00 = __builtin_amdgcn_exp2f(pr * QSCL);
  float L = p00;
  float acc = p00 * v[base0 + c];
#pragma unroll
  for (int i = 0; i < 64; ++i) {
    L += Pl[bh * 64 + i];
    acc += Po[(size_t)(bh * 64 + i) * 64 + c];
  }
  out[(size_t)b * NN * (HN * CN) + h * CN + c] = acc / L;
}

// ---------------- Kernel B: flash attention, 32x32 MFMA, kh-split waves, SPLIT-K x2 ----------------
// Grid 1536: (xcd, bh-chunk, qt, zt). Block zt processes k-tiles [zt*16, zt*16+16).
// No-max softmax => partials merge additively: O = O0+O1, L = L0+L1 (attn_merge kernel).
// Column-0 (p0*v0) terms belong to the zt==0 half only.
__global__ __launch_bounds__(256, 4) void attn_main(
    const float* __restrict__ v,
    const u16* __restrict__ Qr, const u16* __restrict__ Kr, const u16* __restrict__ Vt,
    const float* __restrict__ S0, float* __restrict__ Op, float* __restrict__ Lp) {
  const int wg = blockIdx.x;  // 0..1535; chunked XCD mapping: XCD x owns bh in [3x,3x+3)
  const int inner = wg >> 3;
  const int bh = 3 * (wg & 7) + inner / 64;
  const int rem = inner & 63;
  const int qt = rem >> 1;
  const int zt = rem & 1;
  const int kt0 = zt << 4;
  const int tid = threadIdx.x;
  const int wv = tid >> 6, l = tid & 63;
  const int l31 = l & 31, lh = l >> 5;
  const int qh = wv & 1, kh = wv >> 1;

  __shared__ u16 ldsK[2][4096];  // dbuf 64 tok x 64 c, 8B-swizzled
  __shared__ u16 ldsV[2][4096];  // dbuf 64 c x 64 tok-pos (sigma), 8B-swizzled
  __shared__ float v0f[64];
  __shared__ float Lbuf[64];
  float* Obuf = reinterpret_cast<float*>(&ldsK[0][0]);  // reused post-loop: [2][64][32]

  if (tid < 64) v0f[tid] = v[(size_t)bh * NN * CN + tid];
  __syncthreads();

  // Q B-frags: lane q = l31, c = st*16 + lh*8 + j
  const int qrow = qt * 64 + qh * 32 + l31;
  const u16* qp = Qr + ((size_t)bh * NT + qrow) * CN + lh * 8;
  bf16x8 qf[4];
#pragma unroll
  for (int s = 0; s < 4; ++s) qf[s] = *reinterpret_cast<const bf16x8*>(qp + s * 16);

  const float s0l2 = S0[(size_t)bh * NT + qrow];
  const float p0 = (zt == 0) ? __builtin_amdgcn_exp2f(s0l2) : 0.f;
  float lsum = (zt == 0 && kh == 0 && lh == 0) ? p0 : 0.f;

  // O^T accum: o[half][reg], c = (reg&3) + 8*(reg>>2) + 4*lh + 32*half
  f32x16 o[2];
#pragma unroll
  for (int half = 0; half < 2; ++half)
#pragma unroll
    for (int reg = 0; reg < 16; ++reg)
      o[half][reg] = (zt == 0 && kh == 0)
                         ? p0 * v0f[(reg & 3) + 8 * (reg >> 2) + 4 * lh + 32 * half]
                         : 0.f;

  const u16* Kbh = Kr + (size_t)bh * NT * CN;
  const u16* Vbh = Vt + (size_t)bh * CN * NT;
  char* ldsKc = reinterpret_cast<char*>(&ldsK[0][0]);
  char* ldsVc = reinterpret_cast<char*>(&ldsV[0][0]);

  // staging: thread owns rows srowA/srowB, 16B chunk s16; V uses the SAME offsets (sigma-Vt)
  const int s16 = tid & 7, srowA = tid >> 3, srowB = (tid >> 3) + 32;
  const int swA = (srowA & 15) << 3, swB = (srowB & 15) << 3;
  const int kA0 = srowA * 128 + ((s16 * 16) ^ swA);
  const int kA1 = srowA * 128 + ((s16 * 16 + 8) ^ swA);
  const int kB0 = srowB * 128 + ((s16 * 16) ^ swB);
  const int kB1 = srowB * 128 + ((s16 * 16 + 8) ^ swB);

  f32x4 kreg[2], vrg[2];
#define LOAD_TILE(nx)                                                                       \
  do {                                                                                      \
    kreg[0] = *reinterpret_cast<const f32x4*>(Kbh + (size_t)((nx) + srowA) * CN + s16 * 8); \
    kreg[1] = *reinterpret_cast<const f32x4*>(Kbh + (size_t)((nx) + srowB) * CN + s16 * 8); \
    vrg[0] = *reinterpret_cast<const f32x4*>(Vbh + (size_t)srowA * NT + (nx) + s16 * 8);    \
    vrg[1] = *reinterpret_cast<const f32x4*>(Vbh + (size_t)srowB * NT + (nx) + s16 * 8);    \
  } while (0)

#define WR2(base, off0, off1, vec4)                                           \
  do {                                                                        \
    f32x2 lo_, hi_;                                                           \
    lo_[0] = (vec4)[0]; lo_[1] = (vec4)[1];                                   \
    hi_[0] = (vec4)[2]; hi_[1] = (vec4)[3];                                   \
    *reinterpret_cast<f32x2*>((base) + (off0)) = lo_;                         \
    *reinterpret_cast<f32x2*>((base) + (off1)) = hi_;                         \
  } while (0)

#define STAGE_WRITE(bofs)                        \
  do {                                           \
    WR2(ldsKc + (bofs), kA0, kA1, kreg[0]);      \
    WR2(ldsKc + (bofs), kB0, kB1, kreg[1]);      \
    WR2(ldsVc + (bofs), kA0, kA1, vrg[0]);       \
    WR2(ldsVc + (bofs), kB0, kB1, vrg[1]);       \
  } while (0)

  LOAD_TILE(kt0 * 64);
  STAGE_WRITE(0);
  LOAD_TILE((kt0 + 1) * 64);

#pragma unroll 2
  for (int t = 0; t < 16; ++t) {
    const int kt = kt0 + t;
    const int cur = (t & 1) * 8192;
    const int nxt = ((t + 1) & 1) * 8192;
    __syncthreads();
    if (t < 15) {
      STAGE_WRITE(nxt);
      if (t < 14) LOAD_TILE((kt + 2) * 64);
    }

    // QK^T: S^T (32 toks of this kh x 32 q), contraction over c in 4 steps
    const int trow = kh * 32 + l31;
    const int tsw = (trow & 15) << 3;
    f32x16 S;
#pragma unroll
    for (int reg = 0; reg < 16; ++reg) S[reg] = 0.f;
    __builtin_amdgcn_s_setprio(1);
#pragma unroll
    for (int st = 0; st < 4; ++st) {
      B8 kb;
      const int cb = st * 32 + lh * 16;
      kb.h[0] = *reinterpret_cast<const f32x2*>(ldsKc + cur + trow * 128 + (cb ^ tsw));
      kb.h[1] = *reinterpret_cast<const f32x2*>(ldsKc + cur + trow * 128 + ((cb + 8) ^ tsw));
      S = __builtin_amdgcn_mfma_f32_32x32x16_bf16(kb.v, qf[st], S, 0, 0, 0);
    }
    __builtin_amdgcn_s_setprio(0);

    // P = exp2(S); pack lane-local B-frag words
    PU pa[2];
    {
      float e[16];
#pragma unroll
      for (int reg = 0; reg < 16; ++reg) e[reg] = __builtin_amdgcn_exp2f(S[reg]);
#pragma unroll
      for (int reg = 0; reg < 16; reg += 4)
        lsum += (e[reg] + e[reg + 1]) + (e[reg + 2] + e[reg + 3]);
#pragma unroll
      for (int m = 0; m < 4; ++m) {
        pa[0].u[m] = cvt_pk(e[2 * m], e[2 * m + 1]);
        pa[1].u[m] = cvt_pk(e[8 + 2 * m], e[9 + 2 * m]);
      }
    }

    // PV: O^T += V^T_frag . P over this wave's 2 tok-slices
    __builtin_amdgcn_s_setprio(1);
#pragma unroll
    for (int half = 0; half < 2; ++half) {
      const int crow = half * 32 + l31;
      const int csw = (crow & 15) << 3;
#pragma unroll
      for (int ks = 0; ks < 2; ++ks) {
        B8 vb;
        const int pb = (kh * 2 + ks) * 32 + lh * 16;
        vb.h[0] = *reinterpret_cast<const f32x2*>(ldsVc + cur + crow * 128 + (pb ^ csw));
        vb.h[1] = *reinterpret_cast<const f32x2*>(ldsVc + cur + crow * 128 + ((pb + 8) ^ csw));
        o[half] = __builtin_amdgcn_mfma_f32_32x32x16_bf16(vb.v, pa[ks].v, o[half], 0, 0, 0);
      }
    }
    __builtin_amdgcn_s_setprio(0);
  }

  // ---- epilogue: merge kh partials via LDS; write UNNORMALIZED partial (O, L) ----
  const float wls = lsum + __shfl_xor(lsum, 32, 64);  // reduce over lh
  __syncthreads();                                    // all tile reads done; Obuf reuse safe
  if (kh == 1) {
#pragma unroll
    for (int half = 0; half < 2; ++half)
#pragma unroll
      for (int reg = 0; reg < 16; ++reg) {
        const int c = (reg & 3) + 8 * (reg >> 2) + 4 * lh + 32 * half;
        Obuf[qh * 2048 + c * 32 + l31] = o[half][reg];
      }
    if (lh == 0) Lbuf[qh * 32 + l31] = wls;
  }
  __syncthreads();
  if (kh == 0) {
    const float L = wls + Lbuf[qh * 32 + l31];
    const int pi = (bh * 32 + qt) * 2 + zt;
    const int ql = qh * 32 + l31;
    float* opart = Op + (size_t)pi * 4096 + ql * 64;
#pragma unroll
    for (int half = 0; half < 2; ++half) {
#pragma unroll
      for (int rg = 0; rg < 4; ++rg) {
        f32x4 val;
#pragma unroll
        for (int j = 0; j < 4; ++j) {
          const int reg = 4 * rg + j;
          const int c = (reg & 3) + 8 * (reg >> 2) + 4 * lh + 32 * half;
          val[j] = o[half][reg] + Obuf[qh * 2048 + c * 32 + l31];
        }
        *reinterpret_cast<f32x4*>(opart + 8 * rg + 4 * lh + 32 * half) = val;
      }
    }
    if (lh == 0) Lp[pi * 64 + ql] = L;
  }
#undef LOAD_TILE
#undef WR2
#undef STAGE_WRITE
}

// ---------------- Kernel D: merge split-K partials, normalize, store ----------------
__global__ __launch_bounds__(256) void attn_merge(
    const float* __restrict__ Op, const float* __restrict__ Lp, float* __restrict__ out) {
  const int bh = blockIdx.x, qt = blockIdx.y;
  const int b = bh / HN, h = bh % HN;
  const int tid = threadIdx.x;
  const int ql = tid >> 2;          // 0..63
  const int cg = (tid & 3) * 16;    // 16-col slice
  const int pi = (bh * 32 + qt) * 2;
  const float L = Lp[pi * 64 + ql] + Lp[(pi + 1) * 64 + ql];
  const float invl = 1.0f / L;
  const float* o0 = Op + (size_t)pi * 4096 + ql * 64 + cg;
  const float* o1 = o0 + 4096;
  float* op = out + ((size_t)b * NN + 1 + qt * 64 + ql) * (HN * CN) + h * CN + cg;
#pragma unroll
  for (int j = 0; j < 16; j += 4) {
    f32x4 a = *reinterpret_cast<const f32x4*>(o0 + j);
    f32x4 bb = *reinterpret_cast<const f32x4*>(o1 + j);
    f32x4 r;
#pragma unroll
    for (int jj = 0; jj < 4; ++jj) r[jj] = (a[jj] + bb[jj]) * invl;
    *reinterpret_cast<f32x4*>(op + j) = r;
  }
}

extern "C" void kernel_launch(void* const* d_in, const int* in_sizes, int n_in,
                              void* d_out, int out_size, void* d_ws, size_t ws_size,
                              hipStream_t stream) {
  const float* q = (const float*)d_in[0];
  const float* k = (const float*)d_in[1];
  const float* v = (const float*)d_in[2];
  const int* qpos = (const int*)d_in[3];
  const int* kpos = (const int*)d_in[4];
  float* out = (float*)d_out;

  u16* Qr = (u16*)d_ws;
  u16* Kr = Qr + (size_t)BH * NT * CN;
  u16* Vt = Kr + (size_t)BH * NT * CN;
  float* S0 = (float*)(Vt + (size_t)BH * NT * CN);
  float* Pl = S0 + (size_t)BH * NT;
  float* Po = Pl + BH * 64;
  float* Op = Po + (size_t)BH * 64 * 64;
  float* Lp = Op + (size_t)1536 * 4096;

  rope_pack<<<dim3(BH, 64), 256, 0, stream>>>(q, k, v, qpos, kpos, Qr, Kr, Vt, S0, Pl, Po);
  attn_main<<<dim3(1536), 256, 0, stream>>>(v, Qr, Kr, Vt, S0, Op, Lp);
  attn_merge<<<dim3(BH, 32), 256, 0, stream>>>(Op, Lp, out);
  row0_reduce<<<dim3(BH), 64, 0, stream>>>(q, k, v, Pl, Po, out);
}

// Round 16
// 61.629 us; speedup vs baseline: 1.4982x; 1.4982x over previous
//
#include <hip/hip_runtime.h>
#include <hip/hip_bf16.h>

typedef __attribute__((ext_vector_type(8))) short bf16x8;
typedef __attribute__((ext_vector_type(16))) float f32x16;
typedef __attribute__((ext_vector_type(4))) float f32x4;
typedef __attribute__((ext_vector_type(2))) float f32x2;
typedef unsigned short u16;

#define BN 2
#define HN 12
#define NN 2049
#define CN 64
#define NT 2048
#define BH 24
#define QSCL 0.1803368801111204f /* 0.125 * log2(e) */

__device__ __forceinline__ u16 f2bf(float x) {
  unsigned u = __builtin_bit_cast(unsigned, x);
  unsigned r = (u + 0x7fffu + ((u >> 16) & 1u)) >> 16;
  return (u16)r;
}

__device__ __forceinline__ unsigned cvt_pk(float lo, float hi) {
  unsigned r;
  asm("v_cvt_pk_bf16_f32 %0, %1, %2" : "=v"(r) : "v"(lo), "v"(hi));
  return r;
}

union PU {
  unsigned u[4];
  bf16x8 v;
};
union B8 {
  f32x2 h[2];
  bf16x8 v;
};

// ---------------- Kernel A: rope q,k -> bf16; sigma-transposed v; fused row-0 partials ----------------
// Vt stored [bh][c][gpos], gpos = (T>>6)*64 + sigma(T&63),
// sigma(t6): ch=t6>>3, j=t6&7 -> 16*(ch>>1)+4*(ch&1)+8*(j>>2)+(j&3).
// This matches the attn staging layout, so V stages to LDS with the SAME offsets as K.
__global__ __launch_bounds__(256) void rope_pack(
    const float* __restrict__ q, const float* __restrict__ k, const float* __restrict__ v,
    const int* __restrict__ qpos, const int* __restrict__ kpos,
    u16* __restrict__ Qr, u16* __restrict__ Kr, u16* __restrict__ Vt,
    float* __restrict__ S0, float* __restrict__ Pl, float* __restrict__ Po) {
  const int bh = blockIdx.x;  // 0..23
  const int t = blockIdx.y;   // 0..63 (32-token tiles)
  const int b = bh / HN;
  const int tid = threadIdx.x;
  const int wv = tid >> 6, l = tid & 63;

  __shared__ float lutc[1024], luts[1024];  // idx = pos*16 + f
  __shared__ u16 ldsV[64][36];
  __shared__ float q0s[64], k0s[64];
  __shared__ float osum[4][64];
  __shared__ float psum[4];

  const int n0 = 1 + t * 32;
  const size_t base0 = (size_t)bh * NN * CN;

  const float LF = 6.6438561897747253f / 16.0f;  // log2(100)/16
  for (int i = tid; i < 1024; i += 256) {
    const int pos = i >> 4, f = i & 15;
    const float inv = exp2f(-(float)f * LF);
    float sv, cv;
    sincosf((float)pos * inv, &sv, &cv);
    lutc[i] = cv;
    luts[i] = sv;
  }
  if (tid < 64) {
    q0s[tid] = q[base0 + tid];
    k0s[tid] = k[base0 + tid];
  }
  __syncthreads();

  float oacc = 0.f, pacc = 0.f;
#pragma unroll 2
  for (int i = 0; i < 8; ++i) {
    const int tok = i * 4 + wv;
    const int c = l;
    const int n = n0 + tok;
    const size_t base = base0 + (size_t)n * CN;
    const int cp = c & 31, f = cp & 15, axis = c >> 5;
    const int qp_ = qpos[((size_t)b * NN + n) * 2 + axis];
    const int kp_ = kpos[((size_t)b * NN + n) * 2 + axis];
    const float qa = q[base + c];
    const float ka = k[base + c];
    const float qrot = (cp < 16) ? -q[base + c + 16] : q[base + c - 16];
    const float krot = (cp < 16) ? -k[base + c + 16] : k[base + c - 16];
    Qr[((size_t)bh * NT + (n - 1)) * CN + c] =
        f2bf((qa * lutc[qp_ * 16 + f] + qrot * luts[qp_ * 16 + f]) * QSCL);
    Kr[((size_t)bh * NT + (n - 1)) * CN + c] =
        f2bf(ka * lutc[kp_ * 16 + f] + krot * luts[kp_ * 16 + f]);
    const float vv = v[base + c];
    ldsV[c][tok] = f2bf(vv);

    float pk = ka * q0s[c];
    float pq = qa * k0s[c];
    pk += __shfl_xor(pk, 1, 64);  pq += __shfl_xor(pq, 1, 64);
    pk += __shfl_xor(pk, 2, 64);  pq += __shfl_xor(pq, 2, 64);
    pk += __shfl_xor(pk, 4, 64);  pq += __shfl_xor(pq, 4, 64);
    pk += __shfl_xor(pk, 8, 64);  pq += __shfl_xor(pq, 8, 64);
    pk += __shfl_xor(pk, 16, 64); pq += __shfl_xor(pq, 16, 64);
    pk += __shfl_xor(pk, 32, 64); pq += __shfl_xor(pq, 32, 64);
    const float p = __builtin_amdgcn_exp2f(pk * QSCL);
    pacc += p;
    oacc += p * vv;
    if (l == 0) S0[(size_t)bh * NT + (n - 1)] = pq * QSCL;
  }
  osum[wv][l] = oacc;
  if (l == 0) psum[wv] = pacc;
  __syncthreads();

  for (int e = tid; e < 2048; e += 256) {
    const int c = e >> 5, tok = e & 31;
    const int T = t * 32 + tok;
    const int t6 = T & 63, ch = t6 >> 3, j = t6 & 7;
    const int pos = 16 * (ch >> 1) + 4 * (ch & 1) + 8 * (j >> 2) + (j & 3);
    Vt[((size_t)bh * CN + c) * NT + (T >> 6) * 64 + pos] = ldsV[c][tok];
  }
  if (tid < 64)
    Po[(size_t)(bh * 64 + t) * 64 + tid] =
        osum[0][tid] + osum[1][tid] + osum[2][tid] + osum[3][tid];
  if (tid == 0) Pl[bh * 64 + t] = psum[0] + psum[1] + psum[2] + psum[3];
}

// ---------------- Kernel C: combine row-0 partials (+ token-0 term) ----------------
__global__ __launch_bounds__(64) void row0_reduce(
    const float* __restrict__ q, const float* __restrict__ k, const float* __restrict__ v,
    const float* __restrict__ Pl, const float* __restrict__ Po, float* __restrict__ out) {
  const int bh = blockIdx.x;
  const int b = bh / HN, h = bh % HN;
  const int c = threadIdx.x;
  const size_t base0 = (size_t)bh * NN * CN;
  float pr = q[base0 + c] * k[base0 + c];
  pr += __shfl_xor(pr, 1, 64);
  pr += __shfl_xor(pr, 2, 64);
  pr += __shfl_xor(pr, 4, 64);
  pr += __shfl_xor(pr, 8, 64);
  pr += __shfl_xor(pr, 16, 64);
  pr += __shfl_xor(pr, 32, 64);
  const float p00 = __builtin_amdgcn_exp2f(pr * QSCL);
  float L = p00;
  float acc = p00 * v[base0 + c];
#pragma unroll
  for (int i = 0; i < 64; ++i) {
    L += Pl[bh * 64 + i];
    acc += Po[(size_t)(bh * 64 + i) * 64 + c];
  }
  out[(size_t)b * NN * (HN * CN) + h * CN + c] = acc / L;
}

// ---------------- Kernel B: flash attention, 32x32 MFMA, kh-split waves (r13 empirical optimum) ----------------
// wave wv: qh = wv&1 (32 q-rows), kh = wv>>1 (32 toks of the 64-tile).
// S^T = mfma32(K,Q); PV: O^T = mfma32(V^T, P) with sigma-ordered Vt (stages like K).
// LDS swizzle: byte ^= ((row&15)<<3), b64 accesses (2-way = free).
// One __syncthreads per tile; dbuf; prefetch 2 tiles ahead in registers.
// Measured-worse neighbors: Sa/Sb split (r8), Lacc-MFMA+reorder (r9), 2-tile pipeline (r11),
// no-staging L2-direct (r12), lgkm-only barrier (r14, null), split-K x2 (r15).
__global__ __launch_bounds__(256, 3) void attn_main(
    const float* __restrict__ v,
    const u16* __restrict__ Qr, const u16* __restrict__ Kr, const u16* __restrict__ Vt,
    const float* __restrict__ S0, float* __restrict__ out) {
  const int wg = blockIdx.x;  // 0..767; chunked XCD mapping: XCD x owns bh in [3x,3x+3)
  const int bh = 3 * (wg & 7) + ((wg >> 3) >> 5);
  const int qt = (wg >> 3) & 31;
  const int b = bh / HN, h = bh % HN;
  const int tid = threadIdx.x;
  const int wv = tid >> 6, l = tid & 63;
  const int l31 = l & 31, lh = l >> 5;
  const int qh = wv & 1, kh = wv >> 1;

  __shared__ u16 ldsK[2][4096];  // dbuf 64 tok x 64 c, 8B-swizzled
  __shared__ u16 ldsV[2][4096];  // dbuf 64 c x 64 tok-pos (sigma), 8B-swizzled
  __shared__ float v0f[64];
  __shared__ float Lbuf[64];
  float* Obuf = reinterpret_cast<float*>(&ldsK[0][0]);  // reused post-loop: [2][64][32]

  if (tid < 64) v0f[tid] = v[(size_t)bh * NN * CN + tid];
  __syncthreads();

  // Q B-frags: lane q = l31, c = st*16 + lh*8 + j
  const int qrow = qt * 64 + qh * 32 + l31;
  const u16* qp = Qr + ((size_t)bh * NT + qrow) * CN + lh * 8;
  bf16x8 qf[4];
#pragma unroll
  for (int s = 0; s < 4; ++s) qf[s] = *reinterpret_cast<const bf16x8*>(qp + s * 16);

  const float s0l2 = S0[(size_t)bh * NT + qrow];
  const float p0 = __builtin_amdgcn_exp2f(s0l2);
  float lsum = (kh == 0 && lh == 0) ? p0 : 0.f;

  // O^T accum: o[half][reg], c = (reg&3) + 8*(reg>>2) + 4*lh + 32*half
  f32x16 o[2];
#pragma unroll
  for (int half = 0; half < 2; ++half)
#pragma unroll
    for (int reg = 0; reg < 16; ++reg)
      o[half][reg] =
          (kh == 0) ? p0 * v0f[(reg & 3) + 8 * (reg >> 2) + 4 * lh + 32 * half] : 0.f;

  const u16* Kbh = Kr + (size_t)bh * NT * CN;
  const u16* Vbh = Vt + (size_t)bh * CN * NT;
  char* ldsKc = reinterpret_cast<char*>(&ldsK[0][0]);
  char* ldsVc = reinterpret_cast<char*>(&ldsV[0][0]);

  // staging: thread owns rows srowA/srowB, 16B chunk s16; V uses the SAME offsets (sigma-Vt)
  const int s16 = tid & 7, srowA = tid >> 3, srowB = (tid >> 3) + 32;
  const int swA = (srowA & 15) << 3, swB = (srowB & 15) << 3;
  const int kA0 = srowA * 128 + ((s16 * 16) ^ swA);
  const int kA1 = srowA * 128 + ((s16 * 16 + 8) ^ swA);
  const int kB0 = srowB * 128 + ((s16 * 16) ^ swB);
  const int kB1 = srowB * 128 + ((s16 * 16 + 8) ^ swB);

  f32x4 kreg[2], vrg[2];
#define LOAD_TILE(nx)                                                                       \
  do {                                                                                      \
    kreg[0] = *reinterpret_cast<const f32x4*>(Kbh + (size_t)((nx) + srowA) * CN + s16 * 8); \
    kreg[1] = *reinterpret_cast<const f32x4*>(Kbh + (size_t)((nx) + srowB) * CN + s16 * 8); \
    vrg[0] = *reinterpret_cast<const f32x4*>(Vbh + (size_t)srowA * NT + (nx) + s16 * 8);    \
    vrg[1] = *reinterpret_cast<const f32x4*>(Vbh + (size_t)srowB * NT + (nx) + s16 * 8);    \
  } while (0)

#define WR2(base, off0, off1, vec4)                                           \
  do {                                                                        \
    f32x2 lo_, hi_;                                                           \
    lo_[0] = (vec4)[0]; lo_[1] = (vec4)[1];                                   \
    hi_[0] = (vec4)[2]; hi_[1] = (vec4)[3];                                   \
    *reinterpret_cast<f32x2*>((base) + (off0)) = lo_;                         \
    *reinterpret_cast<f32x2*>((base) + (off1)) = hi_;                         \
  } while (0)

#define STAGE_WRITE(bofs)                        \
  do {                                           \
    WR2(ldsKc + (bofs), kA0, kA1, kreg[0]);      \
    WR2(ldsKc + (bofs), kB0, kB1, kreg[1]);      \
    WR2(ldsVc + (bofs), kA0, kA1, vrg[0]);       \
    WR2(ldsVc + (bofs), kB0, kB1, vrg[1]);       \
  } while (0)

  LOAD_TILE(0);
  STAGE_WRITE(0);
  LOAD_TILE(64);

#pragma unroll 2
  for (int kt = 0; kt < 32; ++kt) {
    const int cur = (kt & 1) * 8192;
    const int nxt = ((kt + 1) & 1) * 8192;
    __syncthreads();
    if (kt < 31) {
      STAGE_WRITE(nxt);
      if (kt < 30) LOAD_TILE((kt + 2) * 64);
    }

    // QK^T: S^T (32 toks of this kh x 32 q), contraction over c in 4 steps
    const int trow = kh * 32 + l31;
    const int tsw = (trow & 15) << 3;
    f32x16 S;
#pragma unroll
    for (int reg = 0; reg < 16; ++reg) S[reg] = 0.f;
    __builtin_amdgcn_s_setprio(1);
#pragma unroll
    for (int st = 0; st < 4; ++st) {
      B8 kb;
      const int cb = st * 32 + lh * 16;
      kb.h[0] = *reinterpret_cast<const f32x2*>(ldsKc + cur + trow * 128 + (cb ^ tsw));
      kb.h[1] = *reinterpret_cast<const f32x2*>(ldsKc + cur + trow * 128 + ((cb + 8) ^ tsw));
      S = __builtin_amdgcn_mfma_f32_32x32x16_bf16(kb.v, qf[st], S, 0, 0, 0);
    }
    __builtin_amdgcn_s_setprio(0);

    // P = exp2(S); pack lane-local B-frag words
    PU pa[2];
    {
      float e[16];
#pragma unroll
      for (int reg = 0; reg < 16; ++reg) e[reg] = __builtin_amdgcn_exp2f(S[reg]);
#pragma unroll
      for (int reg = 0; reg < 16; reg += 4)
        lsum += (e[reg] + e[reg + 1]) + (e[reg + 2] + e[reg + 3]);
#pragma unroll
      for (int m = 0; m < 4; ++m) {
        pa[0].u[m] = cvt_pk(e[2 * m], e[2 * m + 1]);
        pa[1].u[m] = cvt_pk(e[8 + 2 * m], e[9 + 2 * m]);
      }
    }

    // PV: O^T += V^T_frag . P over this wave's 2 tok-slices
    __builtin_amdgcn_s_setprio(1);
#pragma unroll
    for (int half = 0; half < 2; ++half) {
      const int crow = half * 32 + l31;
      const int csw = (crow & 15) << 3;
#pragma unroll
      for (int ks = 0; ks < 2; ++ks) {
        B8 vb;
        const int pb = (kh * 2 + ks) * 32 + lh * 16;
        vb.h[0] = *reinterpret_cast<const f32x2*>(ldsVc + cur + crow * 128 + (pb ^ csw));
        vb.h[1] = *reinterpret_cast<const f32x2*>(ldsVc + cur + crow * 128 + ((pb + 8) ^ csw));
        o[half] = __builtin_amdgcn_mfma_f32_32x32x16_bf16(vb.v, pa[ks].v, o[half], 0, 0, 0);
      }
    }
    __builtin_amdgcn_s_setprio(0);
  }

  // ---- epilogue: merge kh partials via LDS, normalize, store ----
  const float wls = lsum + __shfl_xor(lsum, 32, 64);  // reduce over lh
  __syncthreads();                                    // all tile reads done; Obuf reuse safe
  if (kh == 1) {
#pragma unroll
    for (int half = 0; half < 2; ++half)
#pragma unroll
      for (int reg = 0; reg < 16; ++reg) {
        const int c = (reg & 3) + 8 * (reg >> 2) + 4 * lh + 32 * half;
        Obuf[qh * 2048 + c * 32 + l31] = o[half][reg];
      }
    if (lh == 0) Lbuf[qh * 32 + l31] = wls;
  }
  __syncthreads();
  if (kh == 0) {
    const float L = wls + Lbuf[qh * 32 + l31];
    const float invl = 1.0f / L;
    const int n = 1 + qrow;
    float* op = out + ((size_t)b * NN + n) * (HN * CN) + h * CN;
#pragma unroll
    for (int half = 0; half < 2; ++half) {
#pragma unroll
      for (int rg = 0; rg < 4; ++rg) {
        f32x4 val;
#pragma unroll
        for (int j = 0; j < 4; ++j) {
          const int reg = 4 * rg + j;
          const int c = (reg & 3) + 8 * (reg >> 2) + 4 * lh + 32 * half;
          val[j] = (o[half][reg] + Obuf[qh * 2048 + c * 32 + l31]) * invl;
        }
        *reinterpret_cast<f32x4*>(op + 8 * rg + 4 * lh + 32 * half) = val;
      }
    }
  }
#undef LOAD_TILE
#undef WR2
#undef STAGE_WRITE
}

extern "C" void kernel_launch(void* const* d_in, const int* in_sizes, int n_in,
                              void* d_out, int out_size, void* d_ws, size_t ws_size,
                              hipStream_t stream) {
  const float* q = (const float*)d_in[0];
  const float* k = (const float*)d_in[1];
  const float* v = (const float*)d_in[2];
  const int* qpos = (const int*)d_in[3];
  const int* kpos = (const int*)d_in[4];
  float* out = (float*)d_out;

  u16* Qr = (u16*)d_ws;
  u16* Kr = Qr + (size_t)BH * NT * CN;
  u16* Vt = Kr + (size_t)BH * NT * CN;
  float* S0 = (float*)(Vt + (size_t)BH * NT * CN);
  float* Pl = S0 + (size_t)BH * NT;
  float* Po = Pl + BH * 64;

  rope_pack<<<dim3(BH, 64), 256, 0, stream>>>(q, k, v, qpos, kpos, Qr, Kr, Vt, S0, Pl, Po);
  attn_main<<<dim3(BH * 32), 256, 0, stream>>>(v, Qr, Kr, Vt, S0, out);
  row0_reduce<<<dim3(BH), 64, 0, stream>>>(q, k, v, Pl, Po, out);
}

// Round 17
// 61.077 us; speedup vs baseline: 1.5118x; 1.0090x over previous
//
#include <hip/hip_runtime.h>
#include <hip/hip_bf16.h>

typedef __attribute__((ext_vector_type(8))) short bf16x8;
typedef __attribute__((ext_vector_type(16))) float f32x16;
typedef __attribute__((ext_vector_type(4))) float f32x4;
typedef __attribute__((ext_vector_type(2))) float f32x2;
typedef unsigned short u16;

#define BN 2
#define HN 12
#define NN 2049
#define CN 64
#define NT 2048
#define BH 24
#define QSCL 0.1803368801111204f /* 0.125 * log2(e) */

__device__ __forceinline__ u16 f2bf(float x) {
  unsigned u = __builtin_bit_cast(unsigned, x);
  unsigned r = (u + 0x7fffu + ((u >> 16) & 1u)) >> 16;
  return (u16)r;
}

__device__ __forceinline__ unsigned cvt_pk(float lo, float hi) {
  unsigned r;
  asm("v_cvt_pk_bf16_f32 %0, %1, %2" : "=v"(r) : "v"(lo), "v"(hi));
  return r;
}

union PU {
  unsigned u[4];
  bf16x8 v;
};
union B8 {
  f32x2 h[2];
  bf16x8 v;
};

// ---------------- Kernel A: rope q,k -> bf16 (PRE-SWIZZLED); sigma-transposed v; row-0 partials ----------------
// Kr row r stores element c at index c ^ ((r&15)<<2)  (r = token row in 64-tile space).
// Vt row c (channel) stores sigma-token-position p at index p ^ ((c&15)<<2) within each 64-group.
// => attn_main can DMA LINEAR 16B chunks via global_load_lds and the LDS layout comes out
//    identical to the old swizzled STAGE_WRITE (rule #21 case (c): inverse-swz source + swz read).
__global__ __launch_bounds__(256) void rope_pack(
    const float* __restrict__ q, const float* __restrict__ k, const float* __restrict__ v,
    const int* __restrict__ qpos, const int* __restrict__ kpos,
    u16* __restrict__ Qr, u16* __restrict__ Kr, u16* __restrict__ Vt,
    float* __restrict__ S0, float* __restrict__ Pl, float* __restrict__ Po) {
  const int bh = blockIdx.x;  // 0..23
  const int t = blockIdx.y;   // 0..63 (32-token tiles)
  const int b = bh / HN;
  const int tid = threadIdx.x;
  const int wv = tid >> 6, l = tid & 63;

  __shared__ float lutc[1024], luts[1024];  // idx = pos*16 + f
  __shared__ u16 ldsV[64][36];
  __shared__ float q0s[64], k0s[64];
  __shared__ float osum[4][64];
  __shared__ float psum[4];

  const int n0 = 1 + t * 32;
  const size_t base0 = (size_t)bh * NN * CN;

  const float LF = 6.6438561897747253f / 16.0f;  // log2(100)/16
  for (int i = tid; i < 1024; i += 256) {
    const int pos = i >> 4, f = i & 15;
    const float inv = exp2f(-(float)f * LF);
    float sv, cv;
    sincosf((float)pos * inv, &sv, &cv);
    lutc[i] = cv;
    luts[i] = sv;
  }
  if (tid < 64) {
    q0s[tid] = q[base0 + tid];
    k0s[tid] = k[base0 + tid];
  }
  __syncthreads();

  float oacc = 0.f, pacc = 0.f;
#pragma unroll 2
  for (int i = 0; i < 8; ++i) {
    const int tok = i * 4 + wv;
    const int c = l;
    const int n = n0 + tok;
    const size_t base = base0 + (size_t)n * CN;
    const int cp = c & 31, f = cp & 15, axis = c >> 5;
    const int qp_ = qpos[((size_t)b * NN + n) * 2 + axis];
    const int kp_ = kpos[((size_t)b * NN + n) * 2 + axis];
    const float qa = q[base + c];
    const float ka = k[base + c];
    const float qrot = (cp < 16) ? -q[base + c + 16] : q[base + c - 16];
    const float krot = (cp < 16) ? -k[base + c + 16] : k[base + c - 16];
    Qr[((size_t)bh * NT + (n - 1)) * CN + c] =
        f2bf((qa * lutc[qp_ * 16 + f] + qrot * luts[qp_ * 16 + f]) * QSCL);
    const int rsw = ((n - 1) & 15) << 2;  // K row swizzle (element XOR)
    Kr[((size_t)bh * NT + (n - 1)) * CN + (c ^ rsw)] =
        f2bf(ka * lutc[kp_ * 16 + f] + krot * luts[kp_ * 16 + f]);
    const float vv = v[base + c];
    ldsV[c][tok] = f2bf(vv);

    float pk = ka * q0s[c];
    float pq = qa * k0s[c];
    pk += __shfl_xor(pk, 1, 64);  pq += __shfl_xor(pq, 1, 64);
    pk += __shfl_xor(pk, 2, 64);  pq += __shfl_xor(pq, 2, 64);
    pk += __shfl_xor(pk, 4, 64);  pq += __shfl_xor(pq, 4, 64);
    pk += __shfl_xor(pk, 8, 64);  pq += __shfl_xor(pq, 8, 64);
    pk += __shfl_xor(pk, 16, 64); pq += __shfl_xor(pq, 16, 64);
    pk += __shfl_xor(pk, 32, 64); pq += __shfl_xor(pq, 32, 64);
    const float p = __builtin_amdgcn_exp2f(pk * QSCL);
    pacc += p;
    oacc += p * vv;
    if (l == 0) S0[(size_t)bh * NT + (n - 1)] = pq * QSCL;
  }
  osum[wv][l] = oacc;
  if (l == 0) psum[wv] = pacc;
  __syncthreads();

  for (int e = tid; e < 2048; e += 256) {
    const int c = e >> 5, tok = e & 31;
    const int T = t * 32 + tok;
    const int t6 = T & 63, ch = t6 >> 3, j = t6 & 7;
    const int pos = 16 * (ch >> 1) + 4 * (ch & 1) + 8 * (j >> 2) + (j & 3);
    Vt[((size_t)bh * CN + c) * NT + (T >> 6) * 64 + (pos ^ ((c & 15) << 2))] = ldsV[c][tok];
  }
  if (tid < 64)
    Po[(size_t)(bh * 64 + t) * 64 + tid] =
        osum[0][tid] + osum[1][tid] + osum[2][tid] + osum[3][tid];
  if (tid == 0) Pl[bh * 64 + t] = psum[0] + psum[1] + psum[2] + psum[3];
}

// ---------------- Kernel C: combine row-0 partials (+ token-0 term) ----------------
__global__ __launch_bounds__(64) void row0_reduce(
    const float* __restrict__ q, const float* __restrict__ k, const float* __restrict__ v,
    const float* __restrict__ Pl, const float* __restrict__ Po, float* __restrict__ out) {
  const int bh = blockIdx.x;
  const int b = bh / HN, h = bh % HN;
  const int c = threadIdx.x;
  const size_t base0 = (size_t)bh * NN * CN;
  float pr = q[base0 + c] * k[base0 + c];
  pr += __shfl_xor(pr, 1, 64);
  pr += __shfl_xor(pr, 2, 64);
  pr += __shfl_xor(pr, 4, 64);
  pr += __shfl_xor(pr, 8, 64);
  pr += __shfl_xor(pr, 16, 64);
  pr += __shfl_xor(pr, 32, 64);
  const float p00 = __builtin_amdgcn_exp2f(pr * QSCL);
  float L = p00;
  float acc = p00 * v[base0 + c];
#pragma unroll
  for (int i = 0; i < 64; ++i) {
    L += Pl[bh * 64 + i];
    acc += Po[(size_t)(bh * 64 + i) * 64 + c];
  }
  out[(size_t)b * NN * (HN * CN) + h * CN + c] = acc / L;
}

// ---------------- Kernel B: flash attention, 32x32 MFMA, kh-split, global_load_lds staging ----------------
// wave wv: qh = wv&1 (32 q-rows), kh = wv>>1 (32 toks of the 64-tile).
// Staging: 4x global_load_lds dwordx4 per thread per tile (linear src — Kr/Vt pre-swizzled),
// LDS dest wave-uniform base + lane*16 (lane l of wave w -> row w*8+(l>>3), chunk l&7 — matches
// the old srowA/s16 mapping exactly). One __syncthreads per tile; its vmcnt(0) retires the DMA.
__global__ __launch_bounds__(256, 3) void attn_main(
    const float* __restrict__ v,
    const u16* __restrict__ Qr, const u16* __restrict__ Kr, const u16* __restrict__ Vt,
    const float* __restrict__ S0, float* __restrict__ out) {
  const int wg = blockIdx.x;  // 0..767; chunked XCD mapping: XCD x owns bh in [3x,3x+3)
  const int bh = 3 * (wg & 7) + ((wg >> 3) >> 5);
  const int qt = (wg >> 3) & 31;
  const int b = bh / HN, h = bh % HN;
  const int tid = threadIdx.x;
  const int wv = tid >> 6, l = tid & 63;
  const int l31 = l & 31, lh = l >> 5;
  const int qh = wv & 1, kh = wv >> 1;

  __shared__ u16 ldsK[2][4096];  // dbuf 64 tok x 64 c, pre-swizzled layout
  __shared__ u16 ldsV[2][4096];  // dbuf 64 c x 64 tok-pos (sigma), pre-swizzled layout
  __shared__ float v0f[64];
  __shared__ float Lbuf[64];
  float* Obuf = reinterpret_cast<float*>(&ldsK[0][0]);  // reused post-loop: [2][64][32]

  if (tid < 64) v0f[tid] = v[(size_t)bh * NN * CN + tid];
  __syncthreads();

  // Q B-frags: lane q = l31, c = st*16 + lh*8 + j
  const int qrow = qt * 64 + qh * 32 + l31;
  const u16* qp = Qr + ((size_t)bh * NT + qrow) * CN + lh * 8;
  bf16x8 qf[4];
#pragma unroll
  for (int s = 0; s < 4; ++s) qf[s] = *reinterpret_cast<const bf16x8*>(qp + s * 16);

  const float s0l2 = S0[(size_t)bh * NT + qrow];
  const float p0 = __builtin_amdgcn_exp2f(s0l2);
  float lsum = (kh == 0 && lh == 0) ? p0 : 0.f;

  // O^T accum: o[half][reg], c = (reg&3) + 8*(reg>>2) + 4*lh + 32*half
  f32x16 o[2];
#pragma unroll
  for (int half = 0; half < 2; ++half)
#pragma unroll
    for (int reg = 0; reg < 16; ++reg)
      o[half][reg] =
          (kh == 0) ? p0 * v0f[(reg & 3) + 8 * (reg >> 2) + 4 * lh + 32 * half] : 0.f;

  const u16* Kbh = Kr + (size_t)bh * NT * CN;
  const u16* Vbh = Vt + (size_t)bh * CN * NT;
  char* ldsKc = reinterpret_cast<char*>(&ldsK[0][0]);
  char* ldsVc = reinterpret_cast<char*>(&ldsV[0][0]);

  // staging geometry: thread covers rows srowA (0..31) and srowB (32..63), 16B chunk s16
  const int s16 = tid & 7, srowA = tid >> 3, srowB = (tid >> 3) + 32;

#define DMA_TILE(nx, bofs)                                                                   \
  do {                                                                                       \
    __builtin_amdgcn_global_load_lds(                                                        \
        (const __attribute__((address_space(1))) unsigned int*)(Kbh +                        \
            (size_t)((nx) + srowA) * CN + s16 * 8),                                          \
        (__attribute__((address_space(3))) unsigned int*)(ldsKc + (bofs) + wv * 1024),       \
        16, 0, 0);                                                                           \
    __builtin_amdgcn_global_load_lds(                                                        \
        (const __attribute__((address_space(1))) unsigned int*)(Kbh +                        \
            (size_t)((nx) + srowB) * CN + s16 * 8),                                          \
        (__attribute__((address_space(3))) unsigned int*)(ldsKc + (bofs) + 4096 + wv * 1024),\
        16, 0, 0);                                                                           \
    __builtin_amdgcn_global_load_lds(                                                        \
        (const __attribute__((address_space(1))) unsigned int*)(Vbh +                        \
            (size_t)srowA * NT + (nx) + s16 * 8),                                            \
        (__attribute__((address_space(3))) unsigned int*)(ldsVc + (bofs) + wv * 1024),       \
        16, 0, 0);                                                                           \
    __builtin_amdgcn_global_load_lds(                                                        \
        (const __attribute__((address_space(1))) unsigned int*)(Vbh +                        \
            (size_t)srowB * NT + (nx) + s16 * 8),                                            \
        (__attribute__((address_space(3))) unsigned int*)(ldsVc + (bofs) + 4096 + wv * 1024),\
        16, 0, 0);                                                                           \
  } while (0)

  DMA_TILE(0, 0);

#pragma unroll 2
  for (int kt = 0; kt < 32; ++kt) {
    const int cur = (kt & 1) * 8192;
    const int nxt = ((kt + 1) & 1) * 8192;
    // __syncthreads drains vmcnt(0): DMA for cur has landed; all waves' reads of nxt's
    // old content (tile kt-1) retired before their barrier -> safe to overwrite nxt.
    __syncthreads();
    if (kt < 31) DMA_TILE((kt + 1) * 64, nxt);

    // QK^T: S^T (32 toks of this kh x 32 q), contraction over c in 4 steps
    const int trow = kh * 32 + l31;
    const int tsw = (trow & 15) << 3;
    f32x16 S;
#pragma unroll
    for (int reg = 0; reg < 16; ++reg) S[reg] = 0.f;
    __builtin_amdgcn_s_setprio(1);
#pragma unroll
    for (int st = 0; st < 4; ++st) {
      B8 kb;
      const int cb = st * 32 + lh * 16;
      kb.h[0] = *reinterpret_cast<const f32x2*>(ldsKc + cur + trow * 128 + (cb ^ tsw));
      kb.h[1] = *reinterpret_cast<const f32x2*>(ldsKc + cur + trow * 128 + ((cb + 8) ^ tsw));
      S = __builtin_amdgcn_mfma_f32_32x32x16_bf16(kb.v, qf[st], S, 0, 0, 0);
    }
    __builtin_amdgcn_s_setprio(0);

    // P = exp2(S); pack lane-local B-frag words
    PU pa[2];
    {
      float e[16];
#pragma unroll
      for (int reg = 0; reg < 16; ++reg) e[reg] = __builtin_amdgcn_exp2f(S[reg]);
#pragma unroll
      for (int reg = 0; reg < 16; reg += 4)
        lsum += (e[reg] + e[reg + 1]) + (e[reg + 2] + e[reg + 3]);
#pragma unroll
      for (int m = 0; m < 4; ++m) {
        pa[0].u[m] = cvt_pk(e[2 * m], e[2 * m + 1]);
        pa[1].u[m] = cvt_pk(e[8 + 2 * m], e[9 + 2 * m]);
      }
    }

    // PV: O^T += V^T_frag . P over this wave's 2 tok-slices
    __builtin_amdgcn_s_setprio(1);
#pragma unroll
    for (int half = 0; half < 2; ++half) {
      const int crow = half * 32 + l31;
      const int csw = (crow & 15) << 3;
#pragma unroll
      for (int ks = 0; ks < 2; ++ks) {
        B8 vb;
        const int pb = (kh * 2 + ks) * 32 + lh * 16;
        vb.h[0] = *reinterpret_cast<const f32x2*>(ldsVc + cur + crow * 128 + (pb ^ csw));
        vb.h[1] = *reinterpret_cast<const f32x2*>(ldsVc + cur + crow * 128 + ((pb + 8) ^ csw));
        o[half] = __builtin_amdgcn_mfma_f32_32x32x16_bf16(vb.v, pa[ks].v, o[half], 0, 0, 0);
      }
    }
    __builtin_amdgcn_s_setprio(0);
  }

  // ---- epilogue: merge kh partials via LDS, normalize, store ----
  const float wls = lsum + __shfl_xor(lsum, 32, 64);  // reduce over lh
  __syncthreads();                                    // all tile reads done; Obuf reuse safe
  if (kh == 1) {
#pragma unroll
    for (int half = 0; half < 2; ++half)
#pragma unroll
      for (int reg = 0; reg < 16; ++reg) {
        const int c = (reg & 3) + 8 * (reg >> 2) + 4 * lh + 32 * half;
        Obuf[qh * 2048 + c * 32 + l31] = o[half][reg];
      }
    if (lh == 0) Lbuf[qh * 32 + l31] = wls;
  }
  __syncthreads();
  if (kh == 0) {
    const float L = wls + Lbuf[qh * 32 + l31];
    const float invl = 1.0f / L;
    const int n = 1 + qrow;
    float* op = out + ((size_t)b * NN + n) * (HN * CN) + h * CN;
#pragma unroll
    for (int half = 0; half < 2; ++half) {
#pragma unroll
      for (int rg = 0; rg < 4; ++rg) {
        f32x4 val;
#pragma unroll
        for (int j = 0; j < 4; ++j) {
          const int reg = 4 * rg + j;
          const int c = (reg & 3) + 8 * (reg >> 2) + 4 * lh + 32 * half;
          val[j] = (o[half][reg] + Obuf[qh * 2048 + c * 32 + l31]) * invl;
        }
        *reinterpret_cast<f32x4*>(op + 8 * rg + 4 * lh + 32 * half) = val;
      }
    }
  }
#undef DMA_TILE
}

extern "C" void kernel_launch(void* const* d_in, const int* in_sizes, int n_in,
                              void* d_out, int out_size, void* d_ws, size_t ws_size,
                              hipStream_t stream) {
  const float* q = (const float*)d_in[0];
  const float* k = (const float*)d_in[1];
  const float* v = (const float*)d_in[2];
  const int* qpos = (const int*)d_in[3];
  const int* kpos = (const int*)d_in[4];
  float* out = (float*)d_out;

  u16* Qr = (u16*)d_ws;
  u16* Kr = Qr + (size_t)BH * NT * CN;
  u16* Vt = Kr + (size_t)BH * NT * CN;
  float* S0 = (float*)(Vt + (size_t)BH * NT * CN);
  float* Pl = S0 + (size_t)BH * NT;
  float* Po = Pl + BH * 64;

  rope_pack<<<dim3(BH, 64), 256, 0, stream>>>(q, k, v, qpos, kpos, Qr, Kr, Vt, S0, Pl, Po);
  attn_main<<<dim3(BH * 32), 256, 0, stream>>>(v, Qr, Kr, Vt, S0, out);
  row0_reduce<<<dim3(BH), 64, 0, stream>>>(q, k, v, Pl, Po, out);
}